// Round 5
// baseline (250.421 us; speedup 1.0000x reference)
//
#include <hip/hip_runtime.h>
#include <hip/hip_bf16.h>

#define BB 32
#define NN 4096
#define DDIM 64
#define NCH 8

typedef __attribute__((ext_vector_type(8)))  short bf16x8;
typedef __attribute__((ext_vector_type(16))) float f32x16;
typedef __attribute__((ext_vector_type(4)))  float f32x4;

// packed fp32x2 -> bf16x2 (RNE, v_cvt_pk_bf16_f32 on gfx950)
static __device__ inline unsigned pk(float a, float b) {
  union { __hip_bfloat162 h; unsigned u; } c;
  c.h = __float22bfloat162_rn(float2{a, b});
  return c.u;
}

// ---------------------------------------------------------------------------
// prep_frag: one streaming pass converting E,F,K,V (fp32) into bf16 MFMA
// fragment layout so proj needs NO gather / NO cvt / NO LDS in its hot loop.
//   Ebt/Fbt: [nbg=n/8][col 0..255][j=n%8]   (2 MB each)
//   Kbt/Vbt: [b][nbg=n/8][d 0..63][j=n%8]   (16 MB each)
// ---------------------------------------------------------------------------
__global__ __launch_bounds__(256) void prep_frag(
    const float* __restrict__ Eg, const float* __restrict__ Fg,
    const float* __restrict__ Kg, const float* __restrict__ Vg,
    unsigned short* __restrict__ Ebt, unsigned short* __restrict__ Fbt,
    unsigned short* __restrict__ Kbt, unsigned short* __restrict__ Vbt)
{
  const int blk = blockIdx.x, t = threadIdx.x;
  float v[8];
  if (blk < 1024) {
    const int which = blk >> 9;           // 0=E, 1=F
    const int nbg = blk & 511;            // n-octet group: n = nbg*8 + j
    const float* src = (which ? Fg : Eg) + (long)(nbg * 8) * 256 + t;
    unsigned short* dst = (which ? Fbt : Ebt) + ((long)nbg * 256 + t) * 8;
#pragma unroll
    for (int j = 0; j < 8; ++j) v[j] = src[j * 256];
    union { unsigned u[4]; bf16x8 x; } r;
    r.u[0] = pk(v[0], v[1]); r.u[1] = pk(v[2], v[3]);
    r.u[2] = pk(v[4], v[5]); r.u[3] = pk(v[6], v[7]);
    *(bf16x8*)dst = r.x;
  } else {
    const int kb = blk - 1024;
    const int which = kb >> 12;           // 0=K, 1=V  (4096 blocks each)
    const int kb2 = kb & 4095;
    const int b = kb2 >> 7, nb = kb2 & 127;
    const int g = t >> 6, d = t & 63;
    const int nbg = nb * 4 + g;           // n = nbg*8 + j
    const float* src = (which ? Vg : Kg) + ((long)b * NN + nbg * 8) * 64 + d;
    unsigned short* dst = (which ? Vbt : Kbt)
                        + (long)b * 262144 + ((long)nbg * 64 + d) * 8;
#pragma unroll
    for (int j = 0; j < 8; ++j) v[j] = src[j * 64];
    union { unsigned u[4]; bf16x8 x; } r;
    r.u[0] = pk(v[0], v[1]); r.u[1] = pk(v[2], v[3]);
    r.u[2] = pk(v[4], v[5]); r.u[3] = pk(v[6], v[7]);
    *(bf16x8*)dst = r.x;
  }
}

// ---------------------------------------------------------------------------
// proj_gemm: direct-fragment GEMM (no LDS, no barriers). Per 32-n step:
// 8 coalesced 16B bf16x8 loads (L3-warm from prep) + 8 MFMA.
// Epilogue: device-scope fp32 atomic-add into 4 MB KpP/VpP (zeroed by
// memset) — replaces the 32 MB partial-slab round trip + reduce kernel.
//   mat=0: Kp[k][d] = sum_n E[n][k] K[b][n][d]   (A=BIG(Ebt), B=SML(Kbt))
//   mat=1: Vp[d][k] = sum_n V[b][n][d] F[n][k]   (A=SML(Vbt), B=BIG(Fbt))
// ---------------------------------------------------------------------------
template <int MAT>
static __device__ inline void proj_core5(
    const unsigned short* __restrict__ Bigt,   // frag layout, 256 cols
    const unsigned short* __restrict__ Smlt,   // frag layout, 64 cols (this b)
    float* __restrict__ Cg, int w, int h, int lr, int chunk)
{
  f32x16 acc[2][2];
#pragma unroll
  for (int i = 0; i < 2; ++i)
#pragma unroll
    for (int j = 0; j < 2; ++j)
#pragma unroll
      for (int q = 0; q < 16; ++q) acc[i][j][q] = 0.f;

  const int colB = w * 64 + lr;
  // octets g = h and g = 2+h; step nb = chunk*16 + tt
  const unsigned short* pB0 = Bigt + (((long)chunk * 16 * 4 + h) * 256 + colB) * 8;
  const unsigned short* pB1 = pB0 + 2 * 256 * 8;
  const unsigned short* pS0 = Smlt + (((long)chunk * 16 * 4 + h) * 64 + lr) * 8;
  const unsigned short* pS1 = pS0 + 2 * 64 * 8;

#pragma unroll 4
  for (int tt = 0; tt < 16; ++tt) {
    const long ob = (long)tt * (1024 * 8);   // 4 octets * 256 cols * 8
    const long os = (long)tt * (256 * 8);    // 4 octets * 64 cols * 8
    bf16x8 B0a = *(const bf16x8*)(pB0 + ob);
    bf16x8 B0b = *(const bf16x8*)(pB0 + ob + 32 * 8);
    bf16x8 B1a = *(const bf16x8*)(pB1 + ob);
    bf16x8 B1b = *(const bf16x8*)(pB1 + ob + 32 * 8);
    bf16x8 S0a = *(const bf16x8*)(pS0 + os);
    bf16x8 S0b = *(const bf16x8*)(pS0 + os + 32 * 8);
    bf16x8 S1a = *(const bf16x8*)(pS1 + os);
    bf16x8 S1b = *(const bf16x8*)(pS1 + os + 32 * 8);
    if (MAT == 0) {   // A=BIG (m=k wave-split), B=SML (n=d)
      acc[0][0] = __builtin_amdgcn_mfma_f32_32x32x16_bf16(B0a, S0a, acc[0][0], 0, 0, 0);
      acc[0][1] = __builtin_amdgcn_mfma_f32_32x32x16_bf16(B0a, S0b, acc[0][1], 0, 0, 0);
      acc[1][0] = __builtin_amdgcn_mfma_f32_32x32x16_bf16(B0b, S0a, acc[1][0], 0, 0, 0);
      acc[1][1] = __builtin_amdgcn_mfma_f32_32x32x16_bf16(B0b, S0b, acc[1][1], 0, 0, 0);
      acc[0][0] = __builtin_amdgcn_mfma_f32_32x32x16_bf16(B1a, S1a, acc[0][0], 0, 0, 0);
      acc[0][1] = __builtin_amdgcn_mfma_f32_32x32x16_bf16(B1a, S1b, acc[0][1], 0, 0, 0);
      acc[1][0] = __builtin_amdgcn_mfma_f32_32x32x16_bf16(B1b, S1a, acc[1][0], 0, 0, 0);
      acc[1][1] = __builtin_amdgcn_mfma_f32_32x32x16_bf16(B1b, S1b, acc[1][1], 0, 0, 0);
    } else {          // A=SML (m=d), B=BIG (n=k wave-split)
      acc[0][0] = __builtin_amdgcn_mfma_f32_32x32x16_bf16(S0a, B0a, acc[0][0], 0, 0, 0);
      acc[0][1] = __builtin_amdgcn_mfma_f32_32x32x16_bf16(S0a, B0b, acc[0][1], 0, 0, 0);
      acc[1][0] = __builtin_amdgcn_mfma_f32_32x32x16_bf16(S0b, B0a, acc[1][0], 0, 0, 0);
      acc[1][1] = __builtin_amdgcn_mfma_f32_32x32x16_bf16(S0b, B0b, acc[1][1], 0, 0, 0);
      acc[0][0] = __builtin_amdgcn_mfma_f32_32x32x16_bf16(S1a, B1a, acc[0][0], 0, 0, 0);
      acc[0][1] = __builtin_amdgcn_mfma_f32_32x32x16_bf16(S1a, B1b, acc[0][1], 0, 0, 0);
      acc[1][0] = __builtin_amdgcn_mfma_f32_32x32x16_bf16(S1b, B1a, acc[1][0], 0, 0, 0);
      acc[1][1] = __builtin_amdgcn_mfma_f32_32x32x16_bf16(S1b, B1b, acc[1][1], 0, 0, 0);
    }
  }

  const int mAdd = (MAT == 0) ? w * 64 : 0;
  const int nAdd = (MAT == 0) ? 0 : w * 64;
  const int OS   = (MAT == 0) ? 64 : 256;
#pragma unroll
  for (int mt = 0; mt < 2; ++mt)
#pragma unroll
    for (int nt = 0; nt < 2; ++nt)
#pragma unroll
      for (int i = 0; i < 16; ++i) {
        int ro  = (i & 3) + 8 * (i >> 2) + 4 * h;       // C/D row map
        int row = mAdd + mt * 32 + ro;
        int col = nAdd + nt * 32 + lr;
        // device-scope fp32 atomic add (global_atomic_add_f32)
        __hip_atomic_fetch_add(&Cg[row * OS + col], acc[mt][nt][i],
                               __ATOMIC_RELAXED, __HIP_MEMORY_SCOPE_AGENT);
      }
}

__global__ __launch_bounds__(256, 2) void proj_gemm(
    const unsigned short* __restrict__ Ebt, const unsigned short* __restrict__ Fbt,
    const unsigned short* __restrict__ Kbt, const unsigned short* __restrict__ Vbt,
    float* __restrict__ KpP, float* __restrict__ VpP)
{
  const int blk = blockIdx.x;
  const int chunk = blk % NCH;                    // chunk ~ XCD id -> BIG chunk L2-pinned
  const int mat = (blk / NCH) & 1, b = blk / (2 * NCH);
  const int t = threadIdx.x, w = t >> 6, l = t & 63, h = l >> 5, lr = l & 31;

  if (mat == 0) {
    proj_core5<0>(Ebt, Kbt + (long)b * 262144,
                  KpP + (long)b * 16384, w, h, lr, chunk);
  } else {
    proj_core5<1>(Fbt, Vbt + (long)b * 262144,
                  VpP + (long)b * 16384, w, h, lr, chunk);
  }
}

// ---------------------------------------------------------------------------
// attn2 v3: 1024 blocks x 128 rows (wave owns 32 rows) -> 4 blocks/CU
// (grid, 32KB LDS, VGPR<=128 all allow it; was grid-capped at 2 before).
// Kp fp32 -> bf16 packed ONCE into XOR-swizzled LDS; V frags read fp32 from
// global (L2-resident) and packed inline; LDS reused for O-transpose.
// ---------------------------------------------------------------------------
__global__ __launch_bounds__(256, 4) void attn2_kernel(
    const float* __restrict__ Qg, const float* __restrict__ KpP,
    const float* __restrict__ VpP, float* __restrict__ Og)
{
  __shared__ char smem[32768];              // K-stage (32KB bf16) -> O_lds (32KB f32)

  const int blk = blockIdx.x;
  const int b = blk >> 5, rg = blk & 31;
  const int t = threadIdx.x, w = t >> 6, l = t & 63;
  const int h = l >> 5, lr = l & 31;
  const int row0 = rg * 128 + w * 32;       // wave's 32 Q-rows

  const float* Kp = KpP + (long)b * 16384;  // [k=256][d=64] fp32
  const float* Vp = VpP + (long)b * 16384;  // [d=64][k=256] fp32

  // ---- Q B-frags: B[n=row(lane lr)][k=d contiguous]
  bf16x8 Bq[4];
#pragma unroll
  for (int kk = 0; kk < 4; ++kk) {
    const float* qp = Qg + ((long)b * NN + row0 + lr) * 64 + kk * 16 + h * 8;
    float4 x = *(const float4*)qp;
    float4 y = *(const float4*)(qp + 4);
    union { unsigned u[4]; bf16x8 v; } r;
    r.u[0] = pk(x.x, x.y); r.u[1] = pk(x.z, x.w);
    r.u[2] = pk(y.x, y.y); r.u[3] = pk(y.z, y.w);
    Bq[kk] = r.v;
  }

  // ---- stage Kp -> bf16 swizzled LDS [256 rows x 128B], byte ^= ((row&7)<<4)
  {
    const float4* gk = (const float4*)Kp;
#pragma unroll
    for (int j = 0; j < 16; ++j) {
      int u = j * 256 + t;                  // float4 index (4096 total)
      float4 x = gk[u];
      unsigned lo = pk(x.x, x.y), hi = pk(x.z, x.w);
      int e = u * 4;                        // element index
      int row = e >> 6, col = e & 63;
      int byte = (row * 128 + col * 2) ^ ((row & 7) << 4);
      *(uint2*)(smem + byte) = uint2{lo, hi};
    }
  }
  __syncthreads();

  f32x16 o[2];                              // [d-tile]
#pragma unroll
  for (int dt = 0; dt < 2; ++dt)
#pragma unroll
    for (int q = 0; q < 16; ++q) o[dt][q] = 0.f;
  float rowpart = 0.f;

  union UV { uint4 u; bf16x8 v; };

#pragma unroll
  for (int kt = 0; kt < 8; ++kt) {
    // V A-frags: load fp32 from global (L2), pack immediately
    bf16x8 Av[2][2];
#pragma unroll
    for (int dt = 0; dt < 2; ++dt)
#pragma unroll
      for (int kc = 0; kc < 2; ++kc) {
        const float* vp = Vp + (long)(dt * 32 + lr) * 256 + (kt * 2 + kc) * 16 + h * 8;
        float4 x = *(const float4*)vp;
        float4 y = *(const float4*)(vp + 4);
        union { unsigned u[4]; bf16x8 v; } r;
        r.u[0] = pk(x.x, x.y); r.u[1] = pk(x.z, x.w);
        r.u[2] = pk(y.x, y.y); r.u[3] = pk(y.z, y.w);
        Av[dt][kc] = r.v;
      }

    // Kp A-frags from swizzled LDS: row = kt*32+lr (128B rows)
    bf16x8 Ak[4];
#pragma unroll
    for (int kk = 0; kk < 4; ++kk) {
      int row = kt * 32 + lr;
      int byte = (row * 128 + kk * 32 + h * 16) ^ ((row & 7) << 4);
      Ak[kk] = *(const bf16x8*)(smem + byte);
    }

    f32x16 s;
#pragma unroll
    for (int q = 0; q < 16; ++q) s[q] = 0.f;
#pragma unroll
    for (int kk = 0; kk < 4; ++kk)
      s = __builtin_amdgcn_mfma_f32_32x32x16_bf16(Ak[kk], Bq[kk], s, 0, 0, 0);

    // exp(s/8) = exp2(s*log2(e)/8); no max-subtract (fp32-safe)
    float p[16];
#pragma unroll
    for (int q = 0; q < 16; ++q) p[q] = exp2f(s[q] * 0.1803368801f);
    rowpart += (((p[0] + p[1]) + (p[2] + p[3])) + ((p[4] + p[5]) + (p[6] + p[7])))
             + (((p[8] + p[9]) + (p[10] + p[11])) + ((p[12] + p[13]) + (p[14] + p[15])));

    unsigned wv[8];
#pragma unroll
    for (int m = 0; m < 8; ++m) wv[m] = pk(p[2 * m], p[2 * m + 1]);
    // half-wave exchange: C-layout k=(q&3)+8(q>>2)+4h -> B-layout k=h*8+j
    unsigned r02 = __shfl_xor(h ? wv[0] : wv[2], 32);
    unsigned r13 = __shfl_xor(h ? wv[1] : wv[3], 32);
    unsigned r46 = __shfl_xor(h ? wv[4] : wv[6], 32);
    unsigned r57 = __shfl_xor(h ? wv[5] : wv[7], 32);
    UV c0, c1;
    if (h == 0) {
      c0.u = uint4{wv[0], wv[1], r02, r13};
      c1.u = uint4{wv[4], wv[5], r46, r57};
    } else {
      c0.u = uint4{r02, r13, wv[2], wv[3]};
      c1.u = uint4{r46, r57, wv[6], wv[7]};
    }
    // incremental PV: consume immediately, nothing stays live
    o[0] = __builtin_amdgcn_mfma_f32_32x32x16_bf16(Av[0][0], c0.v, o[0], 0, 0, 0);
    o[0] = __builtin_amdgcn_mfma_f32_32x32x16_bf16(Av[0][1], c1.v, o[0], 0, 0, 0);
    o[1] = __builtin_amdgcn_mfma_f32_32x32x16_bf16(Av[1][0], c0.v, o[1], 0, 0, 0);
    o[1] = __builtin_amdgcn_mfma_f32_32x32x16_bf16(Av[1][1], c1.v, o[1], 0, 0, 0);
  }

  __syncthreads();                          // K-stage reads done; reuse as O_lds
  float* O_lds = (float*)smem;

  // ---- normalize (rowsum at lane=row) and transpose via swizzled LDS
  {
    float rowsum = rowpart + __shfl_xor(rowpart, 32);
    float inv = __builtin_amdgcn_rcpf(rowsum);
    const int r = w * 32 + lr;              // local row 0..127
#pragma unroll
    for (int dt = 0; dt < 2; ++dt)
#pragma unroll
      for (int qg = 0; qg < 4; ++qg) {
        f32x4 vq;
        vq[0] = o[dt][qg * 4 + 0] * inv;
        vq[1] = o[dt][qg * 4 + 1] * inv;
        vq[2] = o[dt][qg * 4 + 2] * inv;
        vq[3] = o[dt][qg * 4 + 3] * inv;
        int cd = dt * 8 + 2 * qg + h;        // d-chunk (4 dwords)
        int cp = cd ^ (r & 15);              // XOR swizzle
        *(f32x4*)&O_lds[r * 64 + cp * 4] = vq;
      }
  }
  __syncthreads();

  const long obase = ((long)b * NN + rg * 128) * 64;
#pragma unroll
  for (int i = 0; i < 8; ++i) {
    int ci = i * 256 + t;
    int rr = ci >> 4, cc = ci & 15, cp = cc ^ (rr & 15);
    *(float4*)(Og + obase + rr * 64 + cc * 4) = *(const float4*)&O_lds[rr * 64 + cp * 4];
  }
}

extern "C" void kernel_launch(void* const* d_in, const int* in_sizes, int n_in,
                              void* d_out, int out_size, void* d_ws, size_t ws_size,
                              hipStream_t stream) {
  const float* Q = (const float*)d_in[0];
  const float* K = (const float*)d_in[1];
  const float* V = (const float*)d_in[2];
  const float* E = (const float*)d_in[3];
  const float* F = (const float*)d_in[4];
  float* out = (float*)d_out;

  // workspace layout (40 MB total)
  char* ws = (char*)d_ws;
  float*          KpP = (float*)(ws);                          // 2 MB fp32 (atomic acc)
  float*          VpP = (float*)(ws + (2l << 20));             // 2 MB
  unsigned short* Ebt = (unsigned short*)(ws + (4l << 20));    // 2 MB
  unsigned short* Fbt = (unsigned short*)(ws + (6l << 20));    // 2 MB
  unsigned short* Kbt = (unsigned short*)(ws + (8l << 20));    // 16 MB
  unsigned short* Vbt = (unsigned short*)(ws + (24l << 20));   // 16 MB

  hipMemsetAsync(ws, 0, 4l << 20, stream);   // zero KpP+VpP for atomic accumulate

  prep_frag<<<dim3(9216), dim3(256), 0, stream>>>(E, F, K, V, Ebt, Fbt, Kbt, Vbt);

  proj_gemm<<<dim3(512), dim3(256), 0, stream>>>(Ebt, Fbt, Kbt, Vbt, KpP, VpP);

  attn2_kernel<<<dim3(1024), dim3(256), 0, stream>>>(Q, KpP, VpP, out);
}

// Round 6
// 197.922 us; speedup vs baseline: 1.2653x; 1.2653x over previous
//
#include <hip/hip_runtime.h>
#include <hip/hip_bf16.h>

#define BB 32
#define NN 4096
#define DDIM 64
#define NCH 8

typedef __attribute__((ext_vector_type(8)))  short bf16x8;
typedef __attribute__((ext_vector_type(16))) float f32x16;
typedef __attribute__((ext_vector_type(4)))  float f32x4;

// packed fp32x2 -> bf16x2 (RNE, v_cvt_pk_bf16_f32 on gfx950)
static __device__ inline unsigned pk(float a, float b) {
  union { __hip_bfloat162 h; unsigned u; } c;
  c.h = __float22bfloat162_rn(float2{a, b});
  return c.u;
}

static __device__ inline bf16x8 pack8(const float* f) {
  union { unsigned u[4]; bf16x8 v; } r;
  r.u[0] = pk(f[0], f[1]); r.u[1] = pk(f[2], f[3]);
  r.u[2] = pk(f[4], f[5]); r.u[3] = pk(f[6], f[7]);
  return r.v;
}

// ---------------------------------------------------------------------------
// proj_gemm v6: r2's LDS-staged pipeline, but 512 threads (8 waves) per
// block -> 16 waves/CU (session audit: occupancy was GRID-capped at 2
// blocks/CU = 8 waves/CU in every prior round). Per-wave work halves
// (acc [2] instead of [2][2]); staging split across all 512 threads.
//   mat=0: Kp[k][d] = sum_n E[n][k] K[b][n][d]   (A=BIG(E),  B=SML(K))
//   mat=1: Vp[d][k] = sum_n V[b][n][d] F[n][k]   (A=SML(V), B=BIG(F))
// ---------------------------------------------------------------------------
template <int MAT>
static __device__ inline void proj_core6(
    const float* __restrict__ Gbig,   // [NN][256] (E or F)
    const float* __restrict__ Gsml,   // [NN][64]  (K[b] or V[b])
    float* __restrict__ Cg,           // fp32 partial out for this (b,chunk)
    unsigned short (*lds)[10240], int chunk)
{
  const int t = threadIdx.x;                 // 0..511
  const int w = t >> 6, l = t & 63, h = l >> 5, lr = l & 31;
  const int hs = t >> 8;                     // BIG row-half selector (0/1)
  const int colB = t & 255;                  // BIG col
  const int gS = (t >> 6) & 3;               // SML octet (t<256)
  const int colS = t & 63;                   // SML col

  const int n00 = chunk * 512;               // 512-n chunk, T=16 steps of 32

  f32x16 acc[2];
#pragma unroll
  for (int j = 0; j < 2; ++j)
#pragma unroll
    for (int q = 0; q < 16; ++q) acc[j][q] = 0.f;

  float xb[16], xs[8], yb[16], ys[8];

  auto loadset = [&](float (&vb)[16], float (&vs)[8], int step) {
    const float* qb = Gbig + (long)(n00 + step * 32 + hs * 16) * 256 + colB;
#pragma unroll
    for (int i = 0; i < 16; ++i) vb[i] = qb[(long)i * 256];
    if (t < 256) {
      const float* qs = Gsml + (long)(n00 + step * 32 + gS * 8) * 64 + colS;
#pragma unroll
      for (int j = 0; j < 8; ++j) vs[j] = qs[(long)j * 64];
    }
  };

  // LDS layout (shorts): BIG frag (g*256 + col)*8, g=0..3 -> [0, 8192)
  //                      SML frag 8192 + (g*64 + col)*8  -> [8192, 10240)
  auto writeset = [&](int buf, float (&vb)[16], float (&vs)[8]) {
#pragma unroll
    for (int gg = 0; gg < 2; ++gg) {
      const int g = hs * 2 + gg;
      *(bf16x8*)&lds[buf][(g * 256 + colB) * 8] = pack8(&vb[gg * 8]);
    }
    if (t < 256)
      *(bf16x8*)&lds[buf][8192 + (gS * 64 + colS) * 8] = pack8(vs);
  };

  auto consume = [&](int buf) {
#pragma unroll
    for (int s2 = 0; s2 < 2; ++s2) {
      const int g = s2 * 2 + h;              // lane's K-octet
      bf16x8 Bg = *(const bf16x8*)&lds[buf][(g * 256 + w * 32 + lr) * 8];
      bf16x8 S0 = *(const bf16x8*)&lds[buf][8192 + (g * 64 + lr) * 8];
      bf16x8 S1 = *(const bf16x8*)&lds[buf][8192 + (g * 64 + 32 + lr) * 8];
      if (MAT == 0) {   // A = BIG (m=k, wave-split 8x32), B = SML (n=d)
        acc[0] = __builtin_amdgcn_mfma_f32_32x32x16_bf16(Bg, S0, acc[0], 0, 0, 0);
        acc[1] = __builtin_amdgcn_mfma_f32_32x32x16_bf16(Bg, S1, acc[1], 0, 0, 0);
      } else {          // A = SML (m=d), B = BIG (n=k, wave-split 8x32)
        acc[0] = __builtin_amdgcn_mfma_f32_32x32x16_bf16(S0, Bg, acc[0], 0, 0, 0);
        acc[1] = __builtin_amdgcn_mfma_f32_32x32x16_bf16(S1, Bg, acc[1], 0, 0, 0);
      }
    }
  };

  loadset(xb, xs, 0);
  loadset(yb, ys, 1);

#pragma unroll 1
  for (int tt = 0; tt < 16; tt += 2) {
    writeset(0, xb, xs);
    if (tt + 2 < 16) loadset(xb, xs, tt + 2);
    __syncthreads();
    consume(0);
    writeset(1, yb, ys);
    if (tt + 3 < 16) loadset(yb, ys, tt + 3);
    __syncthreads();
    consume(1);
  }

#pragma unroll
  for (int j = 0; j < 2; ++j)
#pragma unroll
    for (int i = 0; i < 16; ++i) {
      const int ro = (i & 3) + 8 * (i >> 2) + 4 * h;   // C/D row map (32x32)
      if (MAT == 0) {
        const int row = w * 32 + ro;                   // k
        const int col = j * 32 + lr;                   // d
        Cg[row * 64 + col] = acc[j][i];
      } else {
        const int row = j * 32 + ro;                   // d
        const int col = w * 32 + lr;                   // k
        Cg[row * 256 + col] = acc[j][i];
      }
    }
}

__global__ __launch_bounds__(512, 4) void proj_gemm(
    const float* __restrict__ Kg, const float* __restrict__ Vg,
    const float* __restrict__ Eg, const float* __restrict__ Fg,
    float* __restrict__ KpP, float* __restrict__ VpP)
{
  __shared__ unsigned short lds[2][10240];             // 40 KB

  const int blk = blockIdx.x;
  const int chunk = blk % NCH;
  const int mat = (blk / NCH) & 1, b = blk / (2 * NCH);
  const long PSTR = (long)BB * 16384;

  if (mat == 0) {
    proj_core6<0>(Eg, Kg + (long)b * NN * DDIM,
                  KpP + (long)chunk * PSTR + b * 16384, lds, chunk);
  } else {
    proj_core6<1>(Fg, Vg + (long)b * NN * DDIM,
                  VpP + (long)chunk * PSTR + b * 16384, lds, chunk);
  }
}

// ---------------------------------------------------------------------------
// reduce_cvt: sum NCH fp32 partials -> bf16. grid 1024 (was grid-capped at
// 512): blocks [0,512): Kp, [512,1024): Vp; 4 floats/thread.
// ---------------------------------------------------------------------------
__global__ __launch_bounds__(256) void reduce_cvt(
    const float* __restrict__ KpP, const float* __restrict__ VpP,
    unsigned short* __restrict__ Kpb, unsigned short* __restrict__ Vpb)
{
  const int blk = blockIdx.x;
  const float* src = (blk < 512) ? KpP : VpP;
  unsigned short* dst = (blk < 512) ? Kpb : Vpb;
  const long i = (long)(blk & 511) * 1024 + threadIdx.x * 4;
  float a0 = 0.f, a1 = 0.f, a2 = 0.f, a3 = 0.f;
#pragma unroll
  for (int cch = 0; cch < NCH; ++cch) {
    const float4 p = *(const float4*)(src + (long)cch * (BB * 16384) + i);
    a0 += p.x; a1 += p.y; a2 += p.z; a3 += p.w;
  }
  uint2 o;
  o.x = pk(a0, a1); o.y = pk(a2, a3);
  *(uint2*)(dst + i) = o;
}

// ---------------------------------------------------------------------------
// attn2 v4: r4's bf16 structure, grid un-capped: 1024 blocks x 128 rows,
// wave owns 32 rows (single row-tile; chain halved) -> 4 blocks/CU.
// Kp staged once in XOR-swizzled 32KB LDS (bf16 copy, proven r4 pair);
// V frags 16B bf16 from global (L2-resident); LDS reused for O-transpose.
// ---------------------------------------------------------------------------
__global__ __launch_bounds__(256, 4) void attn2_kernel(
    const float* __restrict__ Qg, const unsigned short* __restrict__ Kpb,
    const unsigned short* __restrict__ Vpb, float* __restrict__ Og)
{
  __shared__ char smem[32768];              // K-stage (32KB bf16) -> O_lds

  const int blk = blockIdx.x;
  const int b = blk >> 5, rg = blk & 31;
  const int t = threadIdx.x, w = t >> 6, l = t & 63;
  const int h = l >> 5, lr = l & 31;
  const int row0 = rg * 128 + w * 32;       // wave's 32 Q-rows

  const unsigned short* Kp = Kpb + (long)b * 16384;   // [k=256][d=64] bf16
  const unsigned short* Vp = Vpb + (long)b * 16384;   // [d=64][k=256] bf16

  // ---- Q B-frags: B[n=row(lane lr)][k=d contiguous]
  bf16x8 Bq[4];
#pragma unroll
  for (int kk = 0; kk < 4; ++kk) {
    const float* qp = Qg + ((long)b * NN + row0 + lr) * 64 + kk * 16 + h * 8;
    float4 x = *(const float4*)qp;
    float4 y = *(const float4*)(qp + 4);
    union { unsigned u[4]; bf16x8 v; } r;
    r.u[0] = pk(x.x, x.y); r.u[1] = pk(x.z, x.w);
    r.u[2] = pk(y.x, y.y); r.u[3] = pk(y.z, y.w);
    Bq[kk] = r.v;
  }

  // ---- stage Kp bf16 [256 rows x 128B] swizzled: byte ^= ((row&7)<<4)
  {
    const uint4* gk = (const uint4*)Kp;
#pragma unroll
    for (int i = 0; i < 8; ++i) {
      int u = i * 256 + t;                               // 16B unit
      uint4 x = gk[u];
      int kbyte = (u * 16) ^ (((u >> 3) & 7) << 4);      // row = u>>3
      *(uint4*)(smem + kbyte) = x;
    }
  }
  __syncthreads();

  f32x16 o[2];                              // [d-tile]
#pragma unroll
  for (int dt = 0; dt < 2; ++dt)
#pragma unroll
    for (int q = 0; q < 16; ++q) o[dt][q] = 0.f;
  float rowpart = 0.f;

  union UV { uint4 u; bf16x8 v; };
  const int swz = (lr & 7) << 4;            // row&7 == lr&7 for rows used

#pragma unroll
  for (int kt = 0; kt < 8; ++kt) {
    // V A-frags from bf16 global (L2-resident)
    bf16x8 Av[2][2];
#pragma unroll
    for (int dt = 0; dt < 2; ++dt)
#pragma unroll
      for (int kc = 0; kc < 2; ++kc)
        Av[dt][kc] = *(const bf16x8*)(Vp + (long)(dt * 32 + lr) * 256 + (kt * 2 + kc) * 16 + h * 8);

    // Kp A-frags from swizzled LDS: row = kt*32+lr (128B rows)
    bf16x8 Ak[4];
#pragma unroll
    for (int kk = 0; kk < 4; ++kk) {
      int byte = ((kt * 32 + lr) * 128 + kk * 32 + h * 16) ^ swz;
      Ak[kk] = *(const bf16x8*)(smem + byte);
    }

    f32x16 s;
#pragma unroll
    for (int q = 0; q < 16; ++q) s[q] = 0.f;
#pragma unroll
    for (int kk = 0; kk < 4; ++kk)
      s = __builtin_amdgcn_mfma_f32_32x32x16_bf16(Ak[kk], Bq[kk], s, 0, 0, 0);

    // exp(s/8) = exp2(s*log2(e)/8); no max-subtract (fp32-safe)
    float p[16];
#pragma unroll
    for (int q = 0; q < 16; ++q) p[q] = exp2f(s[q] * 0.1803368801f);
    rowpart += (((p[0] + p[1]) + (p[2] + p[3])) + ((p[4] + p[5]) + (p[6] + p[7])))
             + (((p[8] + p[9]) + (p[10] + p[11])) + ((p[12] + p[13]) + (p[14] + p[15])));

    unsigned wv[8];
#pragma unroll
    for (int m = 0; m < 8; ++m) wv[m] = pk(p[2 * m], p[2 * m + 1]);
    // half-wave exchange: C-layout k=(q&3)+8(q>>2)+4h -> B-layout k=h*8+j
    unsigned r02 = __shfl_xor(h ? wv[0] : wv[2], 32);
    unsigned r13 = __shfl_xor(h ? wv[1] : wv[3], 32);
    unsigned r46 = __shfl_xor(h ? wv[4] : wv[6], 32);
    unsigned r57 = __shfl_xor(h ? wv[5] : wv[7], 32);
    UV c0, c1;
    if (h == 0) {
      c0.u = uint4{wv[0], wv[1], r02, r13};
      c1.u = uint4{wv[4], wv[5], r46, r57};
    } else {
      c0.u = uint4{r02, r13, wv[2], wv[3]};
      c1.u = uint4{r46, r57, wv[6], wv[7]};
    }
    // incremental PV: consume immediately, nothing stays live
    o[0] = __builtin_amdgcn_mfma_f32_32x32x16_bf16(Av[0][0], c0.v, o[0], 0, 0, 0);
    o[0] = __builtin_amdgcn_mfma_f32_32x32x16_bf16(Av[0][1], c1.v, o[0], 0, 0, 0);
    o[1] = __builtin_amdgcn_mfma_f32_32x32x16_bf16(Av[1][0], c0.v, o[1], 0, 0, 0);
    o[1] = __builtin_amdgcn_mfma_f32_32x32x16_bf16(Av[1][1], c1.v, o[1], 0, 0, 0);
  }

  __syncthreads();                          // K-stage reads done; reuse LDS
  float* O_lds = (float*)smem;

  // ---- normalize (rowsum at lane=row) and transpose via swizzled LDS
  {
    float rowsum = rowpart + __shfl_xor(rowpart, 32);
    float inv = __builtin_amdgcn_rcpf(rowsum);
    const int r = w * 32 + lr;              // local row 0..127
#pragma unroll
    for (int dt = 0; dt < 2; ++dt)
#pragma unroll
      for (int qg = 0; qg < 4; ++qg) {
        f32x4 vq;
        vq[0] = o[dt][qg * 4 + 0] * inv;
        vq[1] = o[dt][qg * 4 + 1] * inv;
        vq[2] = o[dt][qg * 4 + 2] * inv;
        vq[3] = o[dt][qg * 4 + 3] * inv;
        int cd = dt * 8 + 2 * qg + h;        // d-chunk (4 dwords)
        int cp = cd ^ (r & 15);              // XOR swizzle
        *(f32x4*)&O_lds[r * 64 + cp * 4] = vq;
      }
  }
  __syncthreads();

  const long obase = ((long)b * NN + rg * 128) * 64;
#pragma unroll
  for (int i = 0; i < 8; ++i) {
    int ci = i * 256 + t;
    int rr = ci >> 4, cc = ci & 15, cp = cc ^ (rr & 15);
    *(float4*)(Og + obase + rr * 64 + cc * 4) = *(const float4*)&O_lds[rr * 64 + cp * 4];
  }
}

extern "C" void kernel_launch(void* const* d_in, const int* in_sizes, int n_in,
                              void* d_out, int out_size, void* d_ws, size_t ws_size,
                              hipStream_t stream) {
  const float* Q = (const float*)d_in[0];
  const float* K = (const float*)d_in[1];
  const float* V = (const float*)d_in[2];
  const float* E = (const float*)d_in[3];
  const float* F = (const float*)d_in[4];
  float* out = (float*)d_out;

  // workspace layout (34 MB)
  char* ws = (char*)d_ws;
  float*          KpP = (float*)(ws);                          // 16 MB (8 partial chunks)
  float*          VpP = (float*)(ws + (16l << 20));            // 16 MB
  unsigned short* Kpb = (unsigned short*)(ws + (32l << 20));   // 1 MB
  unsigned short* Vpb = (unsigned short*)(ws + (33l << 20));   // 1 MB

  proj_gemm<<<dim3(512), dim3(512), 0, stream>>>(K, V, E, F, KpP, VpP);

  reduce_cvt<<<dim3(1024), dim3(256), 0, stream>>>(KpP, VpP, Kpb, Vpb);

  attn2_kernel<<<dim3(1024), dim3(256), 0, stream>>>(Q, Kpb, Vpb, out);
}